// Round 9
// baseline (164.745 us; speedup 1.0000x reference)
//
#include <hip/hip_runtime.h>
#include <stdint.h>

// GPT-2 attention block, bf16 MFMA. Round 9:
//  - QKV GEMM: V^T epilogue repacked via LDS -> coalesced stores (was 16x
//    write-transaction amplification from b64 scatters at 4KB stride).
//  - proj GEMM: new 64x64-tile kernel, grid 768 (3 blocks/CU; was 192 = 0.75).
//  - flash: 2-buffer XOR parity, single BAR {vmcnt0;BAR;stage;compute},
//    pointer-increment staging (constant strides). Structure else = R5/R8.

constexpr int B_  = 2;
constexpr int S_  = 2048;
constexpr int D_  = 768;
constexpr int N3D = 3 * D_;   // 2304
constexpr int M_  = B_ * S_;  // 4096
constexpr int NTILE = 32 * 24;
#define QSCALE 0.1803368801111f   // 1/sqrt(64) * log2(e)
#define FIXED_M 8.0f

typedef __bf16 bv8 __attribute__((ext_vector_type(8)));
typedef float  fv4 __attribute__((ext_vector_type(4)));
typedef unsigned short uv4 __attribute__((ext_vector_type(4)));
typedef unsigned short uv8 __attribute__((ext_vector_type(8)));

__device__ inline unsigned short f2bf(float x) {
    __bf16 b = (__bf16)x;
    return __builtin_bit_cast(unsigned short, b);
}

__device__ inline fv4 mfma16(bv8 a, bv8 b, fv4 c) {
    return __builtin_amdgcn_mfma_f32_16x16x32_bf16(a, b, c, 0, 0, 0);
}

#define GLOAD_LDS16(g, l)                                                        \
    __builtin_amdgcn_global_load_lds(                                            \
        (__attribute__((address_space(1))) void*)(g),                            \
        (__attribute__((address_space(3))) void*)(l), 16, 0, 0)

#define VMCNT4() asm volatile("s_waitcnt vmcnt(4)" ::: "memory")
#define VMCNT0() asm volatile("s_waitcnt vmcnt(0)" ::: "memory")
#define BAR()                                                                    \
    do { asm volatile("" ::: "memory"); __builtin_amdgcn_s_barrier();            \
         asm volatile("" ::: "memory"); } while (0)

// ---------------------------------------------------------------------------
// Fused prep: [0,1536) cvt hs->bf16 ; [1536,3264) wqkv^T ; [3264,3840) wproj^T
// ---------------------------------------------------------------------------
__global__ __launch_bounds__(256)
void prep(const float* __restrict__ hs, const float* __restrict__ wqkv,
          const float* __restrict__ wproj, unsigned short* __restrict__ hsb,
          unsigned short* __restrict__ wqkvT, unsigned short* __restrict__ wprojT,
          int* __restrict__ cnt)
{
    __shared__ float tl[32][33];
    const int bid = blockIdx.x, t = threadIdx.x;
    if (bid == 0 && t < 4) cnt[t] = 0;

    if (bid < 1536) {
        const size_t i = ((size_t)bid * 256 + t) * 8;
        const float4 a = *(const float4*)&hs[i];
        const float4 b = *(const float4*)&hs[i + 4];
        uv8 o;
        o[0] = f2bf(a.x); o[1] = f2bf(a.y); o[2] = f2bf(a.z); o[3] = f2bf(a.w);
        o[4] = f2bf(b.x); o[5] = f2bf(b.y); o[6] = f2bf(b.z); o[7] = f2bf(b.w);
        *(uv8*)&hsb[i] = o;
        return;
    }

    const float* W;
    unsigned short* WT;
    int K, N, bx, by;
    if (bid < 3264) {
        W = wqkv; WT = wqkvT; K = 768; N = 2304;
        const int b2 = bid - 1536; bx = b2 % 72; by = b2 / 72;
    } else {
        W = wproj; WT = wprojT; K = 768; N = 768;
        const int b2 = bid - 3264; bx = b2 % 24; by = b2 / 24;
    }
    const int n0 = bx * 32, k0 = by * 32;
    {
        const int r = t >> 3, c = (t & 7) * 4;
        const float4 v = *(const float4*)&W[(size_t)(k0 + r) * N + n0 + c];
        tl[r][c + 0] = v.x; tl[r][c + 1] = v.y; tl[r][c + 2] = v.z; tl[r][c + 3] = v.w;
    }
    __syncthreads();
    {
        const int rn = t >> 3, ck = (t & 7) * 4;
        uv4 o;
        o[0] = f2bf(tl[ck + 0][rn]); o[1] = f2bf(tl[ck + 1][rn]);
        o[2] = f2bf(tl[ck + 2][rn]); o[3] = f2bf(tl[ck + 3][rn]);
        *(uv4*)&WT[(size_t)(n0 + rn) * K + k0 + ck] = o;
    }
}

// ---------------------------------------------------------------------------
// QKV GEMM: 128x128 tile, K=768 (constexpr), 3-buffer LDS, 2-deep prefetch,
// single BAR/iter {vmcnt(4); BAR; stage(t+2); compute(t)}.
// Epilogue: Q (x QSCALE) / K / V^T ALL repacked via LDS -> coalesced stores.
// ---------------------------------------------------------------------------
__global__ __launch_bounds__(256)
void gemm_qkv(const unsigned short* __restrict__ A, const unsigned short* __restrict__ BT,
              const float* __restrict__ bias,
              unsigned short* __restrict__ Qb, unsigned short* __restrict__ Kb,
              unsigned short* __restrict__ VTb)
{
    __shared__ unsigned short smem[24576];   // 48KB: 3-buf A|B; epilogue reuses 32KB
    unsigned short* const sA0 = smem;
    unsigned short* const sB0 = smem + 12288;
    constexpr int K = 768, NT = 24;

    const int t = threadIdx.x, w = t >> 6, lane = t & 63;
    const int l15 = lane & 15, l4 = lane >> 4;
    const int orig = blockIdx.x;                     // 576 blocks, gx=18
    const int swz = (orig & 7) * 72 + (orig >> 3);   // bijective XCD swizzle
    const int m0 = (swz / 18) * 128, n0 = (swz % 18) * 128;
    const int wr = w >> 1, wc = w & 1;

    fv4 acc[4][4];
#pragma unroll
    for (int i = 0; i < 4; ++i)
#pragma unroll
        for (int j = 0; j < 4; ++j) acc[i][j] = fv4{0.f, 0.f, 0.f, 0.f};

    const int r0 = w * 16 + (lane >> 2);
    const int c0 = (lane & 3) ^ ((r0 >> 1) & 3);
    const int r1 = (w + 4) * 16 + (lane >> 2);
    const int c1 = (lane & 3) ^ ((r1 >> 1) & 3);

    const unsigned short* ap0 = A  + (size_t)(m0 + r0) * K + c0 * 8;
    const unsigned short* ap1 = A  + (size_t)(m0 + r1) * K + c1 * 8;
    const unsigned short* bp0 = BT + (size_t)(n0 + r0) * K + c0 * 8;
    const unsigned short* bp1 = BT + (size_t)(n0 + r1) * K + c1 * 8;

    auto stage = [&](int buf, int k0) {
        GLOAD_LDS16(ap0 + k0, sA0 + buf * 4096 + w * 512);
        GLOAD_LDS16(ap1 + k0, sA0 + buf * 4096 + (w + 4) * 512);
        GLOAD_LDS16(bp0 + k0, sB0 + buf * 4096 + w * 512);
        GLOAD_LDS16(bp1 + k0, sB0 + buf * 4096 + (w + 4) * 512);
    };

    stage(0, 0);
    stage(1, 32);
    int cur = 0, s2 = 2;
    for (int tt = 0; tt < NT; ++tt) {
        if (tt + 1 < NT) VMCNT4(); else VMCNT0();
        BAR();
        if (tt + 2 < NT) { stage(s2, (tt + 2) * 32); s2 = (s2 == 2) ? 0 : s2 + 1; }

        bv8 af[4], bf[4];
#pragma unroll
        for (int i = 0; i < 4; ++i) {
            const int r = wr * 64 + i * 16 + l15;
            const int c = l4 ^ ((r >> 1) & 3);
            af[i] = *(const bv8*)&sA0[cur * 4096 + r * 32 + c * 8];
        }
#pragma unroll
        for (int j = 0; j < 4; ++j) {
            const int r = wc * 64 + j * 16 + l15;
            const int c = l4 ^ ((r >> 1) & 3);
            bf[j] = *(const bv8*)&sB0[cur * 4096 + r * 32 + c * 8];
        }
        __builtin_amdgcn_s_setprio(1);
#pragma unroll
        for (int i = 0; i < 4; ++i)
#pragma unroll
            for (int j = 0; j < 4; ++j)
                acc[i][j] = mfma16(af[i], bf[j], acc[i][j]);
        __builtin_amdgcn_s_setprio(0);
        cur = (cur == 2) ? 0 : cur + 1;
    }

    const int sect = n0 / 768;           // uniform per block (768 % 128 == 0)
    const int rem0 = n0 - sect * 768;
    const int brow = m0 >> 11, sbase = m0 & 2047, hb = rem0 >> 6;
    __syncthreads();                     // loop done in all waves: smem reusable

    if (sect < 2) {
        // ---- Q/K: acc -> LDS [s 128][d2 128] (chunk-XOR swz), coalesced out ----
        const float qs = (sect == 0) ? QSCALE : 1.0f;
#pragma unroll
        for (int jf = 0; jf < 4; ++jf) {
            const int c = wc * 64 + jf * 16 + l15;
            const float bb = bias[n0 + c];
            const int ch = c >> 3, off = c & 7;
#pragma unroll
            for (int i = 0; i < 4; ++i) {
                const int rb = wr * 64 + i * 16 + l4 * 4;
#pragma unroll
                for (int reg = 0; reg < 4; ++reg) {
                    const int r = rb + reg;
                    smem[r * 128 + ((ch ^ (r & 15)) << 3) + off] =
                        f2bf((acc[i][jf][reg] + bb) * qs);
                }
            }
        }
        __syncthreads();
        unsigned short* const dstQK = (sect == 0) ? Qb : Kb;
#pragma unroll
        for (int u = 0; u < 8; ++u) {
            const int ID = t + 256 * u;
            const int s = ID >> 4, ch = ID & 15;      // ch = hh*8+dc
            const int hh = ch >> 3, dc = ch & 7;
            const uv8 v = *(const uv8*)&smem[s * 128 + ((ch ^ (s & 15)) << 3)];
            const size_t bh = (size_t)brow * 12 + hb + hh;
            *(uv8*)&dstQK[(bh * 2048 + sbase + s) * 64 + dc * 8] = v;
        }
    } else {
        // ---- V: acc -> LDS [d2 128][s 128] (8B-chunk swz), coalesced V^T out ----
#pragma unroll
        for (int jf = 0; jf < 4; ++jf) {
            const int d2 = wc * 64 + jf * 16 + l15;
            const float bb = bias[n0 + d2];
            const int dmask = d2 & 31;
#pragma unroll
            for (int i = 0; i < 4; ++i) {
                const int cs = wr * 16 + i * 4 + l4;  // 8B chunk (4 s-values)
                uv4 pk;
#pragma unroll
                for (int reg = 0; reg < 4; ++reg) pk[reg] = f2bf(acc[i][jf][reg] + bb);
                *(uv4*)&smem[d2 * 128 + ((cs ^ dmask) << 2)] = pk;
            }
        }
        __syncthreads();
#pragma unroll
        for (int u = 0; u < 8; ++u) {
            const int ID = t + 256 * u;
            const int rd = ID >> 4, cp = ID & 15;     // row d2, 16B pair index
            const int k = rd & 31;
            const uv4 a = *(const uv4*)&smem[rd * 128 + (((2 * cp) ^ k) << 2)];
            const uv4 b2 = *(const uv4*)&smem[rd * 128 + (((2 * cp + 1) ^ k) << 2)];
            uv8 v;
            v[0] = a[0]; v[1] = a[1]; v[2] = a[2]; v[3] = a[3];
            v[4] = b2[0]; v[5] = b2[1]; v[6] = b2[2]; v[7] = b2[3];
            const size_t bh = (size_t)brow * 12 + hb + (rd >> 6);
            *(uv8*)&VTb[(bh * 64 + (rd & 63)) * 2048 + sbase + cp * 8] = v;
        }
    }
}

// ---------------------------------------------------------------------------
// Proj GEMM: 64x64 tile, K=768, 4 waves (each 32x32), 2-buffer, 1 BAR/iter.
// Grid 768 -> 3 blocks/CU (was 192 = 0.75/CU). fp32 out + bias.
// ---------------------------------------------------------------------------
__global__ __launch_bounds__(256)
void gemm64(const unsigned short* __restrict__ A, const unsigned short* __restrict__ BT,
            const float* __restrict__ bias, float* __restrict__ Cf)
{
    __shared__ unsigned short sA[2][2048];
    __shared__ unsigned short sB[2][2048];
    constexpr int K = 768, NT = 24;

    const int t = threadIdx.x, w = t >> 6, lane = t & 63;
    const int l15 = lane & 15, l4 = lane >> 4;
    const int orig = blockIdx.x;                     // 768 blocks, gx=12
    const int swz = (orig & 7) * 96 + (orig >> 3);
    const int m0 = (swz / 12) * 64, n0 = (swz % 12) * 64;
    const int wr = w >> 1, wc = w & 1;

    fv4 acc[2][2];
#pragma unroll
    for (int i = 0; i < 2; ++i)
#pragma unroll
        for (int j = 0; j < 2; ++j) acc[i][j] = fv4{0.f, 0.f, 0.f, 0.f};

    const int r0 = w * 16 + (lane >> 2);
    const int c0 = (lane & 3) ^ ((r0 >> 1) & 3);
    const unsigned short* ap = A  + (size_t)(m0 + r0) * K + c0 * 8;
    const unsigned short* bp = BT + (size_t)(n0 + r0) * K + c0 * 8;

    GLOAD_LDS16(ap, sA[0] + w * 512);
    GLOAD_LDS16(bp, sB[0] + w * 512);
    for (int tt = 0; tt < NT; ++tt) {
        const int cur = tt & 1;
        VMCNT0();
        BAR();
        if (tt + 1 < NT) {
            GLOAD_LDS16(ap + (tt + 1) * 32, sA[cur ^ 1] + w * 512);
            GLOAD_LDS16(bp + (tt + 1) * 32, sB[cur ^ 1] + w * 512);
        }
        bv8 af[2], bf[2];
#pragma unroll
        for (int i = 0; i < 2; ++i) {
            const int r = wr * 32 + i * 16 + l15;
            const int c = l4 ^ ((r >> 1) & 3);
            af[i] = *(const bv8*)&sA[cur][r * 32 + c * 8];
        }
#pragma unroll
        for (int j = 0; j < 2; ++j) {
            const int r = wc * 32 + j * 16 + l15;
            const int c = l4 ^ ((r >> 1) & 3);
            bf[j] = *(const bv8*)&sB[cur][r * 32 + c * 8];
        }
        __builtin_amdgcn_s_setprio(1);
#pragma unroll
        for (int i = 0; i < 2; ++i)
#pragma unroll
            for (int j = 0; j < 2; ++j)
                acc[i][j] = mfma16(af[i], bf[j], acc[i][j]);
        __builtin_amdgcn_s_setprio(0);
    }

#pragma unroll
    for (int j = 0; j < 2; ++j) {
        const int col = n0 + wc * 32 + j * 16 + l15;
        const float bb = bias[col];
#pragma unroll
        for (int i = 0; i < 2; ++i) {
            const int rowb = m0 + wr * 32 + i * 16 + l4 * 4;
#pragma unroll
            for (int reg = 0; reg < 4; ++reg)
                Cf[(size_t)(rowb + reg) * 768 + col] = acc[i][j][reg] + bb;
        }
    }
}

// ---------------------------------------------------------------------------
// Flash attention (causal), S^T-swapped MFMA, FIXED-m exp2 softmax.
// 2-buffer XOR parity, 1 BAR/iter {vmcnt0; BAR; stage(t+1); compute(t)},
// pointer-increment staging. Heavy-first atomic queue, 512 blocks.
// ---------------------------------------------------------------------------
__global__ __launch_bounds__(256)
void flash_mfma(const unsigned short* __restrict__ Qb, const unsigned short* __restrict__ Kb,
                const unsigned short* __restrict__ VTb, unsigned short* __restrict__ outb,
                int* __restrict__ cnt)
{
    __shared__ unsigned short sK [2][4096];
    __shared__ unsigned short sVT[2][4096];
    __shared__ unsigned short sP [4][1024];
    __shared__ int sj;

    const int t = threadIdx.x, w = t >> 6, lane = t & 63;
    const int l15 = lane & 15, l4 = lane >> 4;

    const int sr0 = w * 8 + (lane >> 3), sc0 = (lane & 7) ^ (sr0 & 7);
    const int sr1 = (w + 4) * 8 + (lane >> 3), sc1 = (lane & 7) ^ (sr1 & 7);

    for (;;) {
        if (t == 0) sj = atomicAdd(cnt, 1);
        __syncthreads();   // also the job-boundary barrier protecting buffer reuse
        const int j = sj;
        if (j >= NTILE) return;
        const int qt = 31 - j / 24;
        const int bh = j - (j / 24) * 24;
        const int b = bh / 12, h = bh - b * 12;
        const int qrow = qt * 64 + w * 16;

        // per-wave staging pointers; constant strides per kv-iter
        const unsigned short* kp0 = Kb  + (size_t)bh * 131072 + sr0 * 64 + sc0 * 8;
        const unsigned short* kp1 = Kb  + (size_t)bh * 131072 + sr1 * 64 + sc1 * 8;
        const unsigned short* vp0 = VTb + (size_t)bh * 131072 + sr0 * 2048 + sc0 * 8;
        const unsigned short* vp1 = VTb + (size_t)bh * 131072 + sr1 * 2048 + sc1 * 8;

        bv8 qf[2];
        {
            const unsigned short* qp = Qb + ((size_t)bh * 2048 + qrow + l15) * 64 + l4 * 8;
            qf[0] = *(const bv8*)qp;
            qf[1] = *(const bv8*)(qp + 32);
        }

        fv4 o[4];
#pragma unroll
        for (int jf = 0; jf < 4; ++jf) o[jf] = fv4{0.f, 0.f, 0.f, 0.f};
        float l_ = 0.f;

        // prologue: stage tile 0 into buf 0
        GLOAD_LDS16(kp0, &sK[0][w * 512]);
        GLOAD_LDS16(kp1, &sK[0][(w + 4) * 512]);
        GLOAD_LDS16(vp0, &sVT[0][w * 512]);
        GLOAD_LDS16(vp1, &sVT[0][(w + 4) * 512]);
        kp0 += 4096; kp1 += 4096; vp0 += 64; vp1 += 64;

        for (int kt = 0; kt <= qt; ++kt) {
            const int cur = kt & 1;
            VMCNT0();
            BAR();
            if (kt < qt) {
                GLOAD_LDS16(kp0, &sK[cur ^ 1][w * 512]);
                GLOAD_LDS16(kp1, &sK[cur ^ 1][(w + 4) * 512]);
                GLOAD_LDS16(vp0, &sVT[cur ^ 1][w * 512]);
                GLOAD_LDS16(vp1, &sVT[cur ^ 1][(w + 4) * 512]);
                kp0 += 4096; kp1 += 4096; vp0 += 64; vp1 += 64;
            }

            // ---- S^T[kv][q] = K . Q  (acc init = -FIXED_M) ----
            fv4 st[4];
            __builtin_amdgcn_s_setprio(1);
#pragma unroll
            for (int jf = 0; jf < 4; ++jf) {
                st[jf] = fv4{-FIXED_M, -FIXED_M, -FIXED_M, -FIXED_M};
                const int kr = jf * 16 + l15;
#pragma unroll
                for (int hh = 0; hh < 2; ++hh) {
                    const bv8 ka = *(const bv8*)&sK[cur][kr * 64 + (((hh * 4 + l4) ^ (kr & 7)) * 8)];
                    st[jf] = mfma16(ka, qf[hh], st[jf]);
                }
            }
            __builtin_amdgcn_s_setprio(0);

            // ---- P = exp2(st), causal mask on diag tile; accumulate l ----
            float ps[16];
            const int qg = qrow + l15;
            if (kt == qt) {
#pragma unroll
                for (int jf = 0; jf < 4; ++jf)
#pragma unroll
                    for (int reg = 0; reg < 4; ++reg) {
                        const int kvg = kt * 64 + jf * 16 + l4 * 4 + reg;
                        ps[jf * 4 + reg] = (kvg > qg) ? -30000.f : st[jf][reg];
                    }
            } else {
#pragma unroll
                for (int jf = 0; jf < 4; ++jf)
#pragma unroll
                    for (int reg = 0; reg < 4; ++reg) ps[jf * 4 + reg] = st[jf][reg];
            }
            float la0 = 0.f, la1 = 0.f, la2 = 0.f, la3 = 0.f;
#pragma unroll
            for (int u = 0; u < 16; u += 4) {
                const float p0 = exp2f(ps[u + 0]); ps[u + 0] = p0; la0 += p0;
                const float p1 = exp2f(ps[u + 1]); ps[u + 1] = p1; la1 += p1;
                const float p2 = exp2f(ps[u + 2]); ps[u + 2] = p2; la2 += p2;
                const float p3 = exp2f(ps[u + 3]); ps[u + 3] = p3; la3 += p3;
            }
            l_ += (la0 + la1) + (la2 + la3);

            // ---- P -> LDS (packed b64, swizzled, own-wave region) ----
#pragma unroll
            for (int jf = 0; jf < 4; ++jf) {
                uv4 pk;
#pragma unroll
                for (int reg = 0; reg < 4; ++reg) pk[reg] = f2bf(ps[jf * 4 + reg]);
                const int chunk = jf * 2 + (l4 >> 1);
                *(uv4*)&sP[w][l15 * 64 + ((chunk ^ (l15 & 7)) * 8) + (l4 & 1) * 4] = pk;
            }

            // ---- O += P V ----
            bv8 pa[2];
#pragma unroll
            for (int hh = 0; hh < 2; ++hh)
                pa[hh] = *(const bv8*)&sP[w][l15 * 64 + (((hh * 4 + l4) ^ (l15 & 7)) * 8)];
            __builtin_amdgcn_s_setprio(1);
#pragma unroll
            for (int jf = 0; jf < 4; ++jf) {
                const int dr = jf * 16 + l15;
#pragma unroll
                for (int hh = 0; hh < 2; ++hh) {
                    const bv8 vb = *(const bv8*)&sVT[cur][dr * 64 + (((hh * 4 + l4) ^ (dr & 7)) * 8)];
                    o[jf] = mfma16(pa[hh], vb, o[jf]);
                }
            }
            __builtin_amdgcn_s_setprio(0);
        }

        // ---- epilogue: reduce l across l4 group, normalize, store ----
        l_ += __shfl_xor(l_, 16);
        l_ += __shfl_xor(l_, 32);
        const float inv = 1.0f / l_;
        float invq[4];
#pragma unroll
        for (int reg = 0; reg < 4; ++reg) invq[reg] = __shfl(inv, l4 * 4 + reg);
#pragma unroll
        for (int jf = 0; jf < 4; ++jf)
#pragma unroll
            for (int reg = 0; reg < 4; ++reg)
                outb[(size_t)(b * S_ + qrow + l4 * 4 + reg) * D_ + h * 64 + jf * 16 + l15] =
                    f2bf(o[jf][reg] * invq[reg]);
    }
}

// ---------------------------------------------------------------------------
extern "C" void kernel_launch(void* const* d_in, const int* in_sizes, int n_in,
                              void* d_out, int out_size, void* d_ws, size_t ws_size,
                              hipStream_t stream)
{
    const float* hs    = (const float*)d_in[0];
    const float* wqkv  = (const float*)d_in[1];
    const float* bqkv  = (const float*)d_in[2];
    const float* wproj = (const float*)d_in[3];
    const float* bproj = (const float*)d_in[4];
    float* out = (float*)d_out;

    unsigned short* hsb    = (unsigned short*)d_ws;                 // [4096][768]
    unsigned short* wqkvT  = hsb    + (size_t)M_ * D_;              // [2304][768]
    unsigned short* wprojT = wqkvT  + (size_t)N3D * D_;             // [768][768]
    unsigned short* Qb     = wprojT + (size_t)D_ * D_;              // [24][2048][64]
    unsigned short* Kb     = Qb     + (size_t)24 * 2048 * 64;
    unsigned short* VTb    = Kb     + (size_t)24 * 2048 * 64;       // [24][64][2048]
    unsigned short* attnb  = VTb    + (size_t)24 * 2048 * 64;       // [4096][768]
    int* cnt = (int*)(attnb + (size_t)M_ * D_);

    prep<<<3840, 256, 0, stream>>>(hs, wqkv, wproj, hsb, wqkvT, wprojT, cnt);
    gemm_qkv<<<576, 256, 0, stream>>>(hsb, wqkvT, bqkv, Qb, Kb, VTb);
    flash_mfma<<<512, 256, 0, stream>>>(Qb, Kb, VTb, attnb, cnt);
    gemm64<<<768, 256, 0, stream>>>(attnb, wprojT, bproj, out);
}